// Round 3
// baseline (172.408 us; speedup 1.0000x reference)
//
#include <hip/hip_runtime.h>
#include <hip/hip_bf16.h>

typedef __bf16 bf16_t;
typedef bf16_t bf16x4 __attribute__((ext_vector_type(4)));
typedef bf16_t bf16x8 __attribute__((ext_vector_type(8)));
typedef float f32x4 __attribute__((ext_vector_type(4)));

#define MFMA(a, b, c) __builtin_amdgcn_mfma_f32_16x16x32_bf16(a, b, c, 0, 0, 0)

constexpr int B = 8, S = 2048, C = 1024, D = 128;
constexpr float C2 = 0.12751744f; // log2(e)/sqrt(128)

// ---------------- K0: Wt[n][c] = W_sel[c][n], bf16, coalesced via LDS ------
__global__ __launch_bounds__(256) void k_wt(const float* Wq, const float* Wk, const float* Wv, bf16_t* Wt) {
    int ct = blockIdx.x, w = blockIdx.y; // ct 0..63, w 0..2
    const float* src = (w == 0) ? Wq : ((w == 1) ? Wk : Wv);
    __shared__ bf16_t tile[16][132];
    int t = threadIdx.x;
    int cr = t >> 4, dq = t & 15;
    const float* p = src + (size_t)(ct * 16 + cr) * D + dq * 8;
    f32x4 v0 = *(const f32x4*)p;
    f32x4 v1 = *(const f32x4*)(p + 4);
#pragma unroll
    for (int q = 0; q < 4; ++q) { tile[cr][dq * 8 + q] = (bf16_t)v0[q]; tile[cr][dq * 8 + 4 + q] = (bf16_t)v1[q]; }
    __syncthreads();
    int n = t >> 1, g = t & 1;
    bf16x8 o;
#pragma unroll
    for (int cc = 0; cc < 8; ++cc) o[cc] = tile[g * 8 + cc][n];
    *(bf16x8*)(Wt + (size_t)(w * 128 + n) * C + ct * 16 + g * 8) = o;
}

// ---------------- K1: fused QKV projection, X read once -------------------
// 64 rows x 384 cols per block, 8 waves (2 row x 4 col), W frags direct from L2.
__global__ __launch_bounds__(512) void k_qkv(const float* X, const bf16_t* Wt,
                                             bf16_t* Qb, bf16_t* Kb, float* Vf) {
    __shared__ __align__(16) bf16_t xs[2][64 * 32]; // 8 KiB
    int mt = blockIdx.x; // 0..255
    int t = threadIdx.x;
    int lane = t & 63, wid = t >> 6;
    int lr = lane & 15, lg = lane >> 4;
    int wr = wid >> 2, wc = wid & 3; // rows wr*32..+32, cols wc*96..+96
    int rw = mt * 64;
    int xrow = t >> 3, xch = t & 7;
    const float* xsrc = X + (size_t)(rw + xrow) * C + xch * 4;

    f32x4 acc[2][6] = {};
    const bf16_t* wbase = Wt + (size_t)(wc * 96 + lr) * C + lg * 8;

    bf16x8 bbA[6], bbB[6];
#pragma unroll
    for (int nf = 0; nf < 6; ++nf) bbA[nf] = *(const bf16x8*)(wbase + (size_t)nf * 16 * C);
    { // stage X step 0
        f32x4 x = *(const f32x4*)xsrc;
        bf16x4 xv;
#pragma unroll
        for (int q = 0; q < 4; ++q) xv[q] = (bf16_t)x[q];
        *(bf16x4*)&xs[0][xrow * 32 + xch * 4] = xv;
    }
    __syncthreads();

    for (int tt = 0; tt < 32; tt += 2) {
        // even step: compute xs[0]/bbA, prefetch t+1 into xs[1]/bbB
        f32x4 xp;
        if (tt + 1 < 32) {
#pragma unroll
            for (int nf = 0; nf < 6; ++nf) bbB[nf] = *(const bf16x8*)(wbase + (size_t)nf * 16 * C + (tt + 1) * 32);
            xp = *(const f32x4*)(xsrc + (tt + 1) * 32);
        }
        {
            bf16x8 a0 = *(bf16x8*)&xs[0][(wr * 32 + lr) * 32 + lg * 8];
            bf16x8 a1 = *(bf16x8*)&xs[0][(wr * 32 + 16 + lr) * 32 + lg * 8];
#pragma unroll
            for (int nf = 0; nf < 6; ++nf) {
                acc[0][nf] = MFMA(a0, bbA[nf], acc[0][nf]);
                acc[1][nf] = MFMA(a1, bbA[nf], acc[1][nf]);
            }
        }
        if (tt + 1 < 32) {
            bf16x4 xv;
#pragma unroll
            for (int q = 0; q < 4; ++q) xv[q] = (bf16_t)xp[q];
            *(bf16x4*)&xs[1][xrow * 32 + xch * 4] = xv;
        }
        __syncthreads();
        if (tt + 1 >= 32) break;
        // odd step: compute xs[1]/bbB, prefetch t+2 into xs[0]/bbA
        f32x4 xq;
        if (tt + 2 < 32) {
#pragma unroll
            for (int nf = 0; nf < 6; ++nf) bbA[nf] = *(const bf16x8*)(wbase + (size_t)nf * 16 * C + (tt + 2) * 32);
            xq = *(const f32x4*)(xsrc + (tt + 2) * 32);
        }
        {
            bf16x8 a0 = *(bf16x8*)&xs[1][(wr * 32 + lr) * 32 + lg * 8];
            bf16x8 a1 = *(bf16x8*)&xs[1][(wr * 32 + 16 + lr) * 32 + lg * 8];
#pragma unroll
            for (int nf = 0; nf < 6; ++nf) {
                acc[0][nf] = MFMA(a0, bbB[nf], acc[0][nf]);
                acc[1][nf] = MFMA(a1, bbB[nf], acc[1][nf]);
            }
        }
        if (tt + 2 < 32) {
            bf16x4 xv;
#pragma unroll
            for (int q = 0; q < 4; ++q) xv[q] = (bf16_t)xq[q];
            *(bf16x4*)&xs[0][xrow * 32 + xch * 4] = xv;
        }
        __syncthreads();
    }
#pragma unroll
    for (int mi = 0; mi < 2; ++mi)
#pragma unroll
        for (int nf = 0; nf < 6; ++nf) {
            int n = wc * 96 + nf * 16 + lr;
            int sel = n >> 7;
#pragma unroll
            for (int r = 0; r < 4; ++r) {
                size_t m = rw + wr * 32 + mi * 16 + lg * 4 + r;
                float v = acc[mi][nf][r];
                if (sel == 0)      Qb[m * D + n] = (bf16_t)v;
                else if (sel == 1) Kb[m * D + (n - 128)] = (bf16_t)v;
                else               Vf[m * D + (n - 256)] = v;
            }
        }
}

// ---------------- K2: column sums l[j] (8 wave i-octants) + V scale/transpose
__global__ __launch_bounds__(512) void k_sum(const bf16_t* Qb, const bf16_t* Kb,
                                             const float* Vf, bf16_t* Vt) {
    int jt = blockIdx.x, b = blockIdx.y; // jt 0..63
    int tid = threadIdx.x;
    int lane = tid & 63, wid = tid >> 6;
    int lr = lane & 15, lg = lane >> 4;
    int j0 = jt * 32;
    __shared__ __align__(16) bf16_t vtile[128 * 32];
    __shared__ float lsum[8][32];
    __shared__ float linv[32];

    bf16x8 kf[2][4];
#pragma unroll
    for (int jh = 0; jh < 2; ++jh) {
        const bf16x8* kp = (const bf16x8*)(Kb + (size_t)(b * S + j0 + jh * 16 + lr) * D + lg * 8);
#pragma unroll
        for (int kk = 0; kk < 4; ++kk) kf[jh][kk] = kp[kk * 4];
    }
    f32x4 ls0 = {}, ls1 = {};
    for (int ii = 0; ii < 256; ii += 16) {
        int i0 = wid * 256 + ii;
        const bf16x8* qp = (const bf16x8*)(Qb + (size_t)(b * S + i0 + lr) * D + lg * 8);
        bf16x8 q0 = qp[0], q1 = qp[4], q2 = qp[8], q3 = qp[12];
        f32x4 s0 = {}, s1 = {};
        s0 = MFMA(q0, kf[0][0], s0); s0 = MFMA(q1, kf[0][1], s0);
        s0 = MFMA(q2, kf[0][2], s0); s0 = MFMA(q3, kf[0][3], s0);
        s1 = MFMA(q0, kf[1][0], s1); s1 = MFMA(q1, kf[1][1], s1);
        s1 = MFMA(q2, kf[1][2], s1); s1 = MFMA(q3, kf[1][3], s1);
#pragma unroll
        for (int r = 0; r < 4; ++r) {
            ls0[r] += exp2f(s0[r] * C2);
            ls1[r] += exp2f(s1[r] * C2);
        }
    }
    float t0 = ls0[0] + ls0[1] + ls0[2] + ls0[3];
    float t1 = ls1[0] + ls1[1] + ls1[2] + ls1[3];
    t0 += __shfl_xor(t0, 16); t0 += __shfl_xor(t0, 32);
    t1 += __shfl_xor(t1, 16); t1 += __shfl_xor(t1, 32);
    if (lane < 16) { lsum[wid][lane] = t0; lsum[wid][16 + lane] = t1; }
    __syncthreads();
    if (tid < 32) {
        float ssum = 0.f;
#pragma unroll
        for (int w = 0; w < 8; ++w) ssum += lsum[w][tid];
        linv[tid] = 1.0f / ssum;
    }
    __syncthreads();
#pragma unroll
    for (int p = 0; p < 2; ++p) {
        int u = p * 512 + tid;
        int jj = u >> 5, dq = u & 31;
        f32x4 v = *(const f32x4*)(Vf + (size_t)(b * S + j0 + jj) * D + dq * 4);
        float inv = linv[jj];
#pragma unroll
        for (int q = 0; q < 4; ++q) {
            int d = dq * 4 + q;
            vtile[d * 32 + (jj ^ ((d & 3) << 3))] = (bf16_t)(v[q] * inv);
        }
    }
    __syncthreads();
    {
        int u = tid;
        int d = u >> 2, jg = u & 3;
        int col0 = (jg * 8) ^ ((d & 3) << 3);
        bf16x8 row = *(const bf16x8*)&vtile[d * 32 + col0];
        *(bf16x8*)(Vt + (size_t)(b * D + d) * S + j0 + jg * 8) = row;
    }
}

// ---------------- K3: out = exp2(c*QK^T) @ Vt ------------------------------
// 32 i-rows/block, 8 waves = j-eighths (256 j each), swapped QK^T, packed P.
__global__ __launch_bounds__(512) void k_out(const bf16_t* Qb, const bf16_t* Kb,
                                             const bf16_t* Vt, float* Out) {
    int it = blockIdx.x, b = blockIdx.y; // it 0..63
    int tid = threadIdx.x;
    int lane = tid & 63, wid = tid >> 6;
    int lr = lane & 15, lg = lane >> 4;
    int ibase = it * 32;
    __shared__ __align__(16) float sred[8192]; // 32 KiB (P bounce aliased + 2 reduce slots)
    bf16_t* pl = (bf16_t*)((char*)sred + wid * 2560); // [32 rows][stride 40 bf16]

    bf16x8 qf[2][4];
#pragma unroll
    for (int ig = 0; ig < 2; ++ig) {
        const bf16x8* qp = (const bf16x8*)(Qb + (size_t)(b * S + ibase + ig * 16 + lr) * D + lg * 8);
#pragma unroll
        for (int kk = 0; kk < 4; ++kk) qf[ig][kk] = qp[kk * 4];
    }
    f32x4 acc[2][8] = {};
    const bf16_t* vb = Vt + (size_t)b * D * S;
    int jbeg = wid * 256;
    for (int j0 = jbeg; j0 < jbeg + 256; j0 += 32) {
#pragma unroll
        for (int jh = 0; jh < 2; ++jh) {
            const bf16x8* kp = (const bf16x8*)(Kb + (size_t)(b * S + j0 + jh * 16 + lr) * D + lg * 8);
            bf16x8 k0 = kp[0], k1 = kp[4], k2 = kp[8], k3 = kp[12];
#pragma unroll
            for (int ig = 0; ig < 2; ++ig) {
                // swapped: rows = j, cols = i  -> lane holds 4 consecutive j for i=lr
                __builtin_amdgcn_s_setprio(1);
                f32x4 s = {};
                s = MFMA(k0, qf[ig][0], s); s = MFMA(k1, qf[ig][1], s);
                s = MFMA(k2, qf[ig][2], s); s = MFMA(k3, qf[ig][3], s);
                __builtin_amdgcn_s_setprio(0);
                bf16x4 pv;
#pragma unroll
                for (int r = 0; r < 4; ++r) pv[r] = (bf16_t)exp2f(s[r] * C2);
                *(bf16x4*)&pl[(ig * 16 + lr) * 40 + jh * 16 + lg * 4] = pv;
            }
        }
        bf16x8 pa0 = *(const bf16x8*)&pl[lr * 40 + lg * 8];
        bf16x8 pa1 = *(const bf16x8*)&pl[(16 + lr) * 40 + lg * 8];
        __builtin_amdgcn_s_setprio(1);
#pragma unroll
        for (int dc = 0; dc < 8; ++dc) {
            bf16x8 vv = *(const bf16x8*)(vb + (size_t)(dc * 16 + lr) * S + j0 + lg * 8);
            acc[0][dc] = MFMA(pa0, vv, acc[0][dc]);
            acc[1][dc] = MFMA(pa1, vv, acc[1][dc]);
        }
        __builtin_amdgcn_s_setprio(0);
    }

    float* R0 = sred;
    float* R1 = sred + 4096;
    auto wrR = [&](float* R) {
#pragma unroll
        for (int ig = 0; ig < 2; ++ig)
#pragma unroll
            for (int dc = 0; dc < 8; ++dc)
#pragma unroll
                for (int r = 0; r < 4; ++r)
                    R[(ig * 16 + lg * 4 + r) * 128 + dc * 16 + lr] = acc[ig][dc][r];
    };
    auto adR = [&](float* R) {
#pragma unroll
        for (int ig = 0; ig < 2; ++ig)
#pragma unroll
            for (int dc = 0; dc < 8; ++dc)
#pragma unroll
                for (int r = 0; r < 4; ++r)
                    acc[ig][dc][r] += R[(ig * 16 + lg * 4 + r) * 128 + dc * 16 + lr];
    };

    __syncthreads();
    if (wid == 1) wrR(R0); else if (wid == 5) wrR(R1);
    __syncthreads();
    if (wid == 0) adR(R0); else if (wid == 4) adR(R1);
    __syncthreads();
    if (wid == 3) wrR(R0); else if (wid == 7) wrR(R1);
    __syncthreads();
    if (wid == 2) adR(R0); else if (wid == 6) adR(R1);
    __syncthreads();
    if (wid == 2) wrR(R0); else if (wid == 6) wrR(R1);
    __syncthreads();
    if (wid == 0) adR(R0); else if (wid == 4) adR(R1);
    __syncthreads();
    if (wid == 4) wrR(R0);
    __syncthreads();
    if (wid == 0) {
        adR(R0);
#pragma unroll
        for (int ig = 0; ig < 2; ++ig)
#pragma unroll
            for (int dc = 0; dc < 8; ++dc)
#pragma unroll
                for (int r = 0; r < 4; ++r)
                    Out[(size_t)(b * S + ibase + ig * 16 + lg * 4 + r) * D + dc * 16 + lr] = acc[ig][dc][r];
    }
}

extern "C" void kernel_launch(void* const* d_in, const int* in_sizes, int n_in,
                              void* d_out, int out_size, void* d_ws, size_t ws_size,
                              hipStream_t stream) {
    const float* X  = (const float*)d_in[0];
    const float* Wq = (const float*)d_in[1];
    const float* Wk = (const float*)d_in[2];
    const float* Wv = (const float*)d_in[3];
    char* ws = (char*)d_ws;
    bf16_t* Wt = (bf16_t*)(ws);                 // 768 KiB
    bf16_t* Qb = (bf16_t*)(ws + (1ull << 20));  // 4 MiB
    bf16_t* Kb = (bf16_t*)(ws + (5ull << 20));  // 4 MiB
    float*  Vf = (float*)(ws + (9ull << 20));   // 8 MiB
    bf16_t* Vt = (bf16_t*)(ws + (17ull << 20)); // 4 MiB
    float* Out = (float*)d_out;

    k_wt<<<dim3(64, 3), dim3(256), 0, stream>>>(Wq, Wk, Wv, Wt);
    k_qkv<<<dim3(256), dim3(512), 0, stream>>>(X, Wt, Qb, Kb, Vf);
    k_sum<<<dim3(64, 8), dim3(512), 0, stream>>>(Qb, Kb, Vf, Vt);
    k_out<<<dim3(64, 8), dim3(512), 0, stream>>>(Qb, Kb, Vt, Out);
}

// Round 4
// 151.922 us; speedup vs baseline: 1.1348x; 1.1348x over previous
//
#include <hip/hip_runtime.h>
#include <hip/hip_bf16.h>

typedef __bf16 bf16_t;
typedef bf16_t bf16x4 __attribute__((ext_vector_type(4)));
typedef bf16_t bf16x8 __attribute__((ext_vector_type(8)));
typedef float f32x4 __attribute__((ext_vector_type(4)));
typedef __attribute__((address_space(1))) const unsigned int gu32_t;
typedef __attribute__((address_space(3))) unsigned int lu32_t;

#define MFMA(a, b, c) __builtin_amdgcn_mfma_f32_16x16x32_bf16(a, b, c, 0, 0, 0)

constexpr int B = 8, S = 2048, C = 1024, D = 128;
constexpr float C2 = 0.12751744f; // log2(e)/sqrt(128)

// ---------------- K0: Wt[n][c] = W_sel[c][n], bf16, coalesced via LDS ------
__global__ __launch_bounds__(256) void k_wt(const float* Wq, const float* Wk, const float* Wv, bf16_t* Wt) {
    int ct = blockIdx.x, w = blockIdx.y; // ct 0..63, w 0..2
    const float* src = (w == 0) ? Wq : ((w == 1) ? Wk : Wv);
    __shared__ bf16_t tile[16][132];
    int t = threadIdx.x;
    int cr = t >> 4, dq = t & 15;
    const float* p = src + (size_t)(ct * 16 + cr) * D + dq * 8;
    f32x4 v0 = *(const f32x4*)p;
    f32x4 v1 = *(const f32x4*)(p + 4);
#pragma unroll
    for (int q = 0; q < 4; ++q) { tile[cr][dq * 8 + q] = (bf16_t)v0[q]; tile[cr][dq * 8 + 4 + q] = (bf16_t)v1[q]; }
    __syncthreads();
    int n = t >> 1, g = t & 1;
    bf16x8 o;
#pragma unroll
    for (int cc = 0; cc < 8; ++cc) o[cc] = tile[g * 8 + cc][n];
    *(bf16x8*)(Wt + (size_t)(w * 128 + n) * C + ct * 16 + g * 8) = o;
}

// ---------------- K1: fused QKV projection, X read once, W LDS-staged ------
// 64 rows x 384 cols per block, 8 waves (2 row x 4 col), BK=64, dbuf.
// W LDS layout: [ntile(24)][ktile(8)][16 rows][8 k] -> frag reads 2-way-bank free.
__global__ __launch_bounds__(512) void k_qkv(const float* X, const bf16_t* Wt,
                                             bf16_t* Qb, bf16_t* Kb, float* Vf) {
    __shared__ __align__(16) bf16_t wsW[2][24576]; // 2 x 48 KiB
    __shared__ __align__(16) bf16_t wsX[2][4096];  // 2 x 8 KiB
    int mt = blockIdx.x; // 0..255
    int t = threadIdx.x;
    int lane = t & 63, wid = t >> 6;
    int lr = lane & 15, lg = lane >> 4;
    int wr = wid >> 2, wc = wid & 3; // rows wr*32..+32, cols wc*96..+96
    int rw = mt * 64;
    int xrow = t >> 3, xk = t & 7;
    const float* xsrc = X + (size_t)(rw + xrow) * C + xk * 8;
    int xwi = ((xrow >> 4) * 8 + xk) * 128 + (xrow & 15) * 8;

    f32x4 acc[2][6] = {};

    auto stageW = [&](int bufi, int c0) {
#pragma unroll
        for (int q = 0; q < 6; ++q) {
            int nt_ = wid * 3 + (q >> 1);
            int kth = (q & 1) * 4;
            const bf16_t* g = Wt + (size_t)(nt_ * 16 + lr) * C + c0 + (kth + lg) * 8;
            __builtin_amdgcn_global_load_lds((gu32_t*)g,
                (lu32_t*)&wsW[bufi][(nt_ * 8 + kth) * 128], 16, 0, 0);
        }
    };

    { // prologue: stage k-step 0
        stageW(0, 0);
        f32x4 x0 = *(const f32x4*)xsrc;
        f32x4 x1 = *(const f32x4*)(xsrc + 4);
        bf16x8 xv;
#pragma unroll
        for (int q = 0; q < 4; ++q) { xv[q] = (bf16_t)x0[q]; xv[4 + q] = (bf16_t)x1[q]; }
        *(bf16x8*)&wsX[0][xwi] = xv;
        __syncthreads();
    }

    for (int tt = 0; tt < 16; ++tt) {
        int buf = tt & 1, nxt = buf ^ 1;
        f32x4 x0, x1;
        if (tt < 15) { // issue next-step loads early (T14)
            int c0 = (tt + 1) * 64;
            stageW(nxt, c0);
            x0 = *(const f32x4*)(xsrc + c0);
            x1 = *(const f32x4*)(xsrc + c0 + 4);
        }
#pragma unroll
        for (int kh = 0; kh < 2; ++kh) {
            bf16x8 a0 = *(bf16x8*)&wsX[buf][((wr * 2 + 0) * 8 + kh * 4 + lg) * 128 + lr * 8];
            bf16x8 a1 = *(bf16x8*)&wsX[buf][((wr * 2 + 1) * 8 + kh * 4 + lg) * 128 + lr * 8];
#pragma unroll
            for (int nf = 0; nf < 6; ++nf) {
                bf16x8 bb = *(bf16x8*)&wsW[buf][((wc * 6 + nf) * 8 + kh * 4 + lg) * 128 + lr * 8];
                acc[0][nf] = MFMA(a0, bb, acc[0][nf]);
                acc[1][nf] = MFMA(a1, bb, acc[1][nf]);
            }
        }
        if (tt < 15) { // write-late X into next buffer
            bf16x8 xv;
#pragma unroll
            for (int q = 0; q < 4; ++q) { xv[q] = (bf16_t)x0[q]; xv[4 + q] = (bf16_t)x1[q]; }
            *(bf16x8*)&wsX[nxt][xwi] = xv;
        }
        __syncthreads();
    }
#pragma unroll
    for (int mi = 0; mi < 2; ++mi)
#pragma unroll
        for (int nf = 0; nf < 6; ++nf) {
            int n = wc * 96 + nf * 16 + lr;
            int sel = (wc * 96 + nf * 16) >> 7; // wave-uniform
#pragma unroll
            for (int r = 0; r < 4; ++r) {
                size_t m = rw + wr * 32 + mi * 16 + lg * 4 + r;
                float v = acc[mi][nf][r];
                if (sel == 0)      Qb[m * D + n] = (bf16_t)v;
                else if (sel == 1) Kb[m * D + (n - 128)] = (bf16_t)v;
                else               Vf[m * D + (n - 256)] = v;
            }
        }
}

// ---------------- K2: column sums l[j] over 64-j blocks + V scale/transpose
__global__ __launch_bounds__(512) void k_sum(const bf16_t* Qb, const bf16_t* Kb,
                                             const float* Vf, bf16_t* Vt) {
    int l = blockIdx.x;          // 256 blocks
    int b = l & 7, jt = l >> 3;  // b pinned to XCD; jt 0..31
    int j0 = jt * 64;
    int tid = threadIdx.x;
    int lane = tid & 63, wid = tid >> 6;
    int lr = lane & 15, lg = lane >> 4;
    __shared__ __align__(16) bf16_t vtile[128 * 64]; // 16 KiB
    __shared__ float lsum[8][64];
    __shared__ float linv[64];

    bf16x8 kf[4][4];
#pragma unroll
    for (int jx = 0; jx < 4; ++jx) {
        const bf16x8* kp = (const bf16x8*)(Kb + (size_t)(b * S + j0 + jx * 16 + lr) * D + lg * 8);
#pragma unroll
        for (int kk = 0; kk < 4; ++kk) kf[jx][kk] = kp[kk * 4];
    }
    f32x4 ls[4] = {};
    for (int ii = 0; ii < 256; ii += 16) {
        int i0 = wid * 256 + ii;
        const bf16x8* qp = (const bf16x8*)(Qb + (size_t)(b * S + i0 + lr) * D + lg * 8);
        bf16x8 q0 = qp[0], q1 = qp[4], q2 = qp[8], q3 = qp[12];
#pragma unroll
        for (int jx = 0; jx < 4; ++jx) {
            f32x4 s = {};
            s = MFMA(q0, kf[jx][0], s); s = MFMA(q1, kf[jx][1], s);
            s = MFMA(q2, kf[jx][2], s); s = MFMA(q3, kf[jx][3], s);
#pragma unroll
            for (int r = 0; r < 4; ++r) ls[jx][r] += exp2f(s[r] * C2);
        }
    }
#pragma unroll
    for (int jx = 0; jx < 4; ++jx) {
        float tv = ls[jx][0] + ls[jx][1] + ls[jx][2] + ls[jx][3];
        tv += __shfl_xor(tv, 16); tv += __shfl_xor(tv, 32);
        if (lane < 16) lsum[wid][jx * 16 + lr] = tv;
    }
    __syncthreads();
    if (tid < 64) {
        float ssum = 0.f;
#pragma unroll
        for (int w = 0; w < 8; ++w) ssum += lsum[w][tid];
        linv[tid] = 1.0f / ssum;
    }
    __syncthreads();
    // scale + transpose V: vtile[d][col ^ ((d>>2 & 7)<<3)]
#pragma unroll
    for (int p = 0; p < 4; ++p) {
        int u = p * 512 + tid;
        int jj = u >> 5, dq = u & 31;
        f32x4 v = *(const f32x4*)(Vf + (size_t)(b * S + j0 + jj) * D + dq * 4);
        float inv = linv[jj];
        int colx = jj ^ ((dq & 7) << 3);
#pragma unroll
        for (int q = 0; q < 4; ++q)
            vtile[(dq * 4 + q) * 64 + colx] = (bf16_t)(v[q] * inv);
    }
    __syncthreads();
#pragma unroll
    for (int p = 0; p < 2; ++p) {
        int u = p * 512 + tid;
        int d = u >> 3, jg = u & 7;
        int colx = (jg * 8) ^ (((d >> 2) & 7) << 3);
        bf16x8 row = *(const bf16x8*)&vtile[d * 64 + colx];
        *(bf16x8*)(Vt + (size_t)(b * D + d) * S + j0 + jg * 8) = row;
    }
}

// ---------------- K3: out = exp2(c*QK^T) @ Vt ------------------------------
// 64 i-rows/block (2 i-halves x 4 j-quarters of 512 j), b pinned to XCD.
__global__ __launch_bounds__(512) void k_out(const bf16_t* Qb, const bf16_t* Kb,
                                             const bf16_t* Vt, float* Out) {
    int l = blockIdx.x;          // 256 blocks
    int b = l & 7, it = l >> 3;  // it 0..31
    int ibase = it * 64;
    int tid = threadIdx.x;
    int lane = tid & 63, wid = tid >> 6;
    int lr = lane & 15, lg = lane >> 4;
    int ig2 = wid >> 2, jq = wid & 3;
    __shared__ __align__(16) float sred[8192];        // 32 KiB (P bounce aliased + 2 reduce slots)
    bf16_t* pl = (bf16_t*)((char*)sred + wid * 2560); // [32 rows][stride 40 bf16]

    bf16x8 qf[2][4];
#pragma unroll
    for (int ig = 0; ig < 2; ++ig) {
        const bf16x8* qp = (const bf16x8*)(Qb + (size_t)(b * S + ibase + ig2 * 32 + ig * 16 + lr) * D + lg * 8);
#pragma unroll
        for (int kk = 0; kk < 4; ++kk) qf[ig][kk] = qp[kk * 4];
    }
    f32x4 acc[2][8] = {};
    const bf16_t* vb = Vt + (size_t)b * D * S;
    int jbeg = jq * 512;
    for (int j0 = jbeg; j0 < jbeg + 512; j0 += 32) {
#pragma unroll
        for (int jh = 0; jh < 2; ++jh) {
            const bf16x8* kp = (const bf16x8*)(Kb + (size_t)(b * S + j0 + jh * 16 + lr) * D + lg * 8);
            bf16x8 k0 = kp[0], k1 = kp[4], k2 = kp[8], k3 = kp[12];
#pragma unroll
            for (int ig = 0; ig < 2; ++ig) {
                // swapped: lane holds S^T[j = j0+jh*16+lg*4+r][i = lr]
                f32x4 s = {};
                s = MFMA(k0, qf[ig][0], s); s = MFMA(k1, qf[ig][1], s);
                s = MFMA(k2, qf[ig][2], s); s = MFMA(k3, qf[ig][3], s);
                bf16x4 pv;
#pragma unroll
                for (int r = 0; r < 4; ++r) pv[r] = (bf16_t)exp2f(s[r] * C2);
                *(bf16x4*)&pl[(ig * 16 + lr) * 40 + jh * 16 + lg * 4] = pv;
            }
        }
        bf16x8 pa0 = *(const bf16x8*)&pl[lr * 40 + lg * 8];
        bf16x8 pa1 = *(const bf16x8*)&pl[(16 + lr) * 40 + lg * 8];
        __builtin_amdgcn_s_setprio(1);
#pragma unroll
        for (int dc = 0; dc < 8; ++dc) {
            bf16x8 vv = *(const bf16x8*)(vb + (size_t)(dc * 16 + lr) * S + j0 + lg * 8);
            acc[0][dc] = MFMA(pa0, vv, acc[0][dc]);
            acc[1][dc] = MFMA(pa1, vv, acc[1][dc]);
        }
        __builtin_amdgcn_s_setprio(0);
    }

    float* Rk = sred + ig2 * 4096; // per-i-half reduce slot (16 KiB each)
    auto wrR = [&]() {
#pragma unroll
        for (int ig = 0; ig < 2; ++ig)
#pragma unroll
            for (int dc = 0; dc < 8; ++dc)
#pragma unroll
                for (int r = 0; r < 4; ++r)
                    Rk[(ig * 16 + lg * 4 + r) * 128 + dc * 16 + lr] = acc[ig][dc][r];
    };
    auto adR = [&]() {
#pragma unroll
        for (int ig = 0; ig < 2; ++ig)
#pragma unroll
            for (int dc = 0; dc < 8; ++dc)
#pragma unroll
                for (int r = 0; r < 4; ++r)
                    acc[ig][dc][r] += Rk[(ig * 16 + lg * 4 + r) * 128 + dc * 16 + lr];
    };

    __syncthreads();
    if (jq == 1) wrR();
    __syncthreads();
    if (jq == 0) adR();
    __syncthreads();
    if (jq == 3) wrR();
    __syncthreads();
    if (jq == 2) adR();
    __syncthreads();
    if (jq == 2) wrR();
    __syncthreads();
    if (jq == 0) {
        adR();
#pragma unroll
        for (int ig = 0; ig < 2; ++ig)
#pragma unroll
            for (int dc = 0; dc < 8; ++dc)
#pragma unroll
                for (int r = 0; r < 4; ++r)
                    Out[(size_t)(b * S + ibase + ig2 * 32 + ig * 16 + lg * 4 + r) * D + dc * 16 + lr] = acc[ig][dc][r];
    }
}

extern "C" void kernel_launch(void* const* d_in, const int* in_sizes, int n_in,
                              void* d_out, int out_size, void* d_ws, size_t ws_size,
                              hipStream_t stream) {
    const float* X  = (const float*)d_in[0];
    const float* Wq = (const float*)d_in[1];
    const float* Wk = (const float*)d_in[2];
    const float* Wv = (const float*)d_in[3];
    char* ws = (char*)d_ws;
    bf16_t* Wt = (bf16_t*)(ws);                 // 768 KiB
    bf16_t* Qb = (bf16_t*)(ws + (1ull << 20));  // 4 MiB
    bf16_t* Kb = (bf16_t*)(ws + (5ull << 20));  // 4 MiB
    float*  Vf = (float*)(ws + (9ull << 20));   // 8 MiB
    bf16_t* Vt = (bf16_t*)(ws + (17ull << 20)); // 4 MiB
    float* Out = (float*)d_out;

    k_wt<<<dim3(64, 3), dim3(256), 0, stream>>>(Wq, Wk, Wv, Wt);
    k_qkv<<<dim3(256), dim3(512), 0, stream>>>(X, Wt, Qb, Kb, Vf);
    k_sum<<<dim3(256), dim3(512), 0, stream>>>(Qb, Kb, Vf, Vt);
    k_out<<<dim3(256), dim3(512), 0, stream>>>(Qb, Kb, Vt, Out);
}

// Round 6
// 103.876 us; speedup vs baseline: 1.6597x; 1.4625x over previous
//
#include <hip/hip_runtime.h>
#include <hip/hip_bf16.h>

typedef __bf16 bf16_t;
typedef bf16_t bf16x4 __attribute__((ext_vector_type(4)));
typedef bf16_t bf16x8 __attribute__((ext_vector_type(8)));
typedef float f32x4 __attribute__((ext_vector_type(4)));
typedef __attribute__((address_space(1))) const unsigned int gu32_t;
typedef __attribute__((address_space(3))) unsigned int lu32_t;

#define MFMA(a, b, c) __builtin_amdgcn_mfma_f32_16x16x32_bf16(a, b, c, 0, 0, 0)

constexpr int B = 8, S = 2048, C = 1024, D = 128;
constexpr float C2 = 0.12751744f; // log2(e)/sqrt(128)

// Frag-major layout: frag(blk16, kk) = 1KB block; lane l = ((k>>3)&3)*16 + (m16&15),
// holds 8 contiguous k at q = k&7. Same map serves A-operand (m=lane&15) and
// B-operand (n=lane&15) of mfma_16x16x32.

// ---------------- K0: W[c][n] -> Wf frag-major (B-operand, k=c, n-dim=col) --
__global__ __launch_bounds__(256) void k_wt(const float* Wq, const float* Wk, const float* Wv, bf16_t* Wf) {
    int ct = blockIdx.x, w = blockIdx.y; // ct 0..63 (16-c rows), w 0..2
    const float* src = (w == 0) ? Wq : ((w == 1) ? Wk : Wv);
    __shared__ bf16_t tile[16][132];
    int t = threadIdx.x;
    int cr = t >> 4, dq = t & 15;
    const float* p = src + (size_t)(ct * 16 + cr) * D + dq * 8;
    f32x4 v0 = *(const f32x4*)p;
    f32x4 v1 = *(const f32x4*)(p + 4);
#pragma unroll
    for (int q = 0; q < 4; ++q) { tile[cr][dq * 8 + q] = (bf16_t)v0[q]; tile[cr][dq * 8 + 4 + q] = (bf16_t)v1[q]; }
    __syncthreads();
    int n = t >> 1, g = t & 1; // n 0..127, g = 8-c half
    bf16x8 o;
#pragma unroll
    for (int cc = 0; cc < 8; ++cc) o[cc] = tile[g * 8 + cc][n];
    int c8 = ct * 2 + g;           // c-8-chunk index 0..127
    int nblk = w * 8 + (n >> 4);   // 0..23
    size_t a = ((size_t)(nblk * 32 + (c8 >> 2)) * 64 + (c8 & 3) * 16 + (n & 15)) * 8;
    *(bf16x8*)(Wf + a) = o;
}

// ---------------- K1: fused QKV projection -------------------------------
// 64 rows x 384 cols per block; 8 waves = 8 col-slices of 48; X in LDS dbuf;
// W frags coalesced from L2; outputs Qf/Kf frag-major, Vf fp32 row-major.
__global__ __launch_bounds__(512) void k_qkv(const float* X, const bf16_t* Wf,
                                             bf16_t* Qf, bf16_t* Kf, float* Vf) {
    __shared__ __align__(16) bf16_t xs[2][4096]; // [4 rblk][8 kchunk][16][8]
    int mt = blockIdx.x; // 0..255
    int t = threadIdx.x;
    int lane = t & 63, wid = t >> 6;
    int lr = lane & 15, lg = lane >> 4;
    int rw = mt * 64;
    int xrow = t >> 3, xk = t & 7;
    const float* xsrc = X + (size_t)(rw + xrow) * C + xk * 8;
    int xwi = ((xrow >> 4) * 8 + xk) * 128 + (xrow & 15) * 8;

    f32x4 acc[4][3] = {};

    { // stage X step 0
        f32x4 x0 = *(const f32x4*)xsrc;
        f32x4 x1 = *(const f32x4*)(xsrc + 4);
        bf16x8 xv;
#pragma unroll
        for (int q = 0; q < 4; ++q) { xv[q] = (bf16_t)x0[q]; xv[4 + q] = (bf16_t)x1[q]; }
        *(bf16x8*)&xs[0][xwi] = xv;
    }
    __syncthreads();

    for (int tt = 0; tt < 16; ++tt) {
        int buf = tt & 1;
        bf16x8 w0[3], w1[3];
#pragma unroll
        for (int nf = 0; nf < 3; ++nf) {
            w0[nf] = *(const bf16x8*)(Wf + ((size_t)((wid * 3 + nf) * 32 + tt * 2) * 64 + lane) * 8);
            w1[nf] = *(const bf16x8*)(Wf + ((size_t)((wid * 3 + nf) * 32 + tt * 2 + 1) * 64 + lane) * 8);
        }
        f32x4 xp0, xp1;
        if (tt < 15) {
            xp0 = *(const f32x4*)(xsrc + (tt + 1) * 64);
            xp1 = *(const f32x4*)(xsrc + (tt + 1) * 64 + 4);
        }
#pragma unroll
        for (int rF = 0; rF < 4; ++rF) {
            bf16x8 a0 = *(bf16x8*)&xs[buf][(rF * 8 + lg) * 128 + lr * 8];
            bf16x8 a1 = *(bf16x8*)&xs[buf][(rF * 8 + 4 + lg) * 128 + lr * 8];
#pragma unroll
            for (int nf = 0; nf < 3; ++nf) {
                acc[rF][nf] = MFMA(a0, w0[nf], acc[rF][nf]);
                acc[rF][nf] = MFMA(a1, w1[nf], acc[rF][nf]);
            }
        }
        if (tt < 15) {
            bf16x8 xv;
#pragma unroll
            for (int q = 0; q < 4; ++q) { xv[q] = (bf16_t)xp0[q]; xv[4 + q] = (bf16_t)xp1[q]; }
            *(bf16x8*)&xs[buf ^ 1][xwi] = xv;
        }
        __syncthreads();
    }
    // epilogue: scatter to frag-major Qf/Kf (bf16) or row-major Vf (fp32)
#pragma unroll
    for (int rF = 0; rF < 4; ++rF)
#pragma unroll
        for (int nf = 0; nf < 3; ++nf) {
            int n = wid * 48 + nf * 16 + lr;
            int sel = (wid * 48 + nf * 16) >> 7; // wave-uniform
            int nn = n & 127;
#pragma unroll
            for (int r = 0; r < 4; ++r) {
                int m = rw + rF * 16 + lg * 4 + r;
                float v = acc[rF][nf][r];
                if (sel == 2) {
                    Vf[(size_t)m * D + nn] = v;
                } else {
                    bf16_t* dst = (sel == 0) ? Qf : Kf;
                    size_t a = ((size_t)((m >> 4) * 4 + (nn >> 5)) * 64 + ((nn >> 3) & 3) * 16 + (m & 15)) * 8 + (nn & 7);
                    dst[a] = (bf16_t)v;
                }
            }
        }
}

// ---------------- K2: column sums l[j] + V scale/transpose to Vt2 ---------
// block = 64 j x full i-sweep; Q staged dbuf via linear global_load_lds;
// K frags in regs; epilogue writes Vt2 frag-major (PV B-operand).
__global__ __launch_bounds__(512) void k_sum(const bf16_t* Qf, const bf16_t* Kf,
                                             const float* Vf, bf16_t* Vt2) {
    int l = blockIdx.x;          // 256 blocks
    int b = l & 7, jt = l >> 3;  // b pinned to XCD; jt 0..31
    int j0 = jt * 64;
    int t = threadIdx.x;
    int lane = t & 63, wid = t >> 6;
    int lr = lane & 15;
    __shared__ __align__(16) bf16_t qs[2][16384]; // 2 x 32 KiB
    bf16_t* vtile = qs[0];                        // 16 KiB (alias, post-loop)
    float* lsum = (float*)(qs[0] + 8192);         // 2 KiB
    float* linv = (float*)(qs[0] + 9216);         // 256 B

    bf16x8 kf[4][4];
    int jblkg = (b * S + j0) >> 4;
#pragma unroll
    for (int jF = 0; jF < 4; ++jF)
#pragma unroll
        for (int kk = 0; kk < 4; ++kk)
            kf[jF][kk] = *(const bf16x8*)(Kf + ((size_t)((jblkg + jF) * 4 + kk) * 64 + lane) * 8);

    const bf16_t* qsrc = Qf + (size_t)(b * S) * 128;
    auto stageQ = [&](int bufi, int i0) {
#pragma unroll
        for (int i = 0; i < 4; ++i)
            __builtin_amdgcn_global_load_lds(
                (gu32_t*)(qsrc + (size_t)i0 * 128 + wid * 2048 + i * 512 + lane * 8),
                (lu32_t*)&qs[bufi][wid * 2048 + i * 512], 16, 0, 0);
    };

    float ls[4] = {0.f, 0.f, 0.f, 0.f};
    stageQ(0, 0);
    __syncthreads();
    for (int tt = 0; tt < 16; ++tt) {
        int buf = tt & 1;
        if (tt < 15) stageQ(buf ^ 1, (tt + 1) * 128);
        bf16x8 qa[4];
#pragma unroll
        for (int kk = 0; kk < 4; ++kk)
            qa[kk] = *(const bf16x8*)&qs[buf][(wid * 4 + kk) * 512 + lane * 8];
        f32x4 s[4] = {};
#pragma unroll
        for (int kk = 0; kk < 4; ++kk) {
            s[0] = MFMA(qa[kk], kf[0][kk], s[0]);
            s[1] = MFMA(qa[kk], kf[1][kk], s[1]);
            s[2] = MFMA(qa[kk], kf[2][kk], s[2]);
            s[3] = MFMA(qa[kk], kf[3][kk], s[3]);
        }
#pragma unroll
        for (int jF = 0; jF < 4; ++jF)
#pragma unroll
            for (int r = 0; r < 4; ++r) ls[jF] += exp2f(s[jF][r] * C2);
        __syncthreads();
    }
#pragma unroll
    for (int jF = 0; jF < 4; ++jF) {
        float v = ls[jF];
        v += __shfl_xor(v, 16); v += __shfl_xor(v, 32);
        if (lane < 16) lsum[wid * 64 + jF * 16 + lane] = v;
    }
    __syncthreads();
    if (t < 64) {
        float ss = 0.f;
#pragma unroll
        for (int w = 0; w < 8; ++w) ss += lsum[w * 64 + t];
        linv[t] = 1.0f / ss;
    }
    __syncthreads();
    // scale + transpose V into vtile (swizzled), then emit frag-major Vt2
#pragma unroll
    for (int p = 0; p < 4; ++p) {
        int u = p * 512 + t;
        int jj = u >> 5, dq = u & 31;
        f32x4 v = *(const f32x4*)(Vf + (size_t)(b * S + j0 + jj) * D + dq * 4);
        float inv = linv[jj];
        int colx = jj ^ ((dq & 7) << 3);
#pragma unroll
        for (int q = 0; q < 4; ++q)
            vtile[(dq * 4 + q) * 64 + colx] = (bf16_t)(v[q] * inv);
    }
    __syncthreads();
#pragma unroll
    for (int p = 0; p < 2; ++p) {
        int u = p * 512 + t;
        int d = u >> 3, jg = u & 7;
        int colx = (jg * 8) ^ (((d >> 2) & 7) << 3);
        bf16x8 row = *(const bf16x8*)&vtile[d * 64 + colx];
        // BUGFIX r6: include batch offset (b*64 j32-slices) — was missing, all
        // 8 b's clobbered the same region while k_out read Vt2 + b*D*S.
        size_t j32g = (size_t)b * 64 + (j0 >> 5) + (jg >> 2);
        size_t a = ((j32g * 8 + (d >> 4)) * 64 + (jg & 3) * 16 + (d & 15)) * 8;
        *(bf16x8*)(Vt2 + a) = row;
    }
}

// ---------------- K3: out = exp2(c*QK^T) @ Vdiv ---------------------------
// 256 blocks = 8 b x 16 it(128 i) x 2 jh(1024 j); 8 waves = 4 ig(32 i) x 2 jq.
// K tile dbuf-staged (linear frag copy), V frags coalesced from L2, atomicAdd out.
__global__ __launch_bounds__(512) void k_out(const bf16_t* Qf, const bf16_t* Kf,
                                             const bf16_t* Vt2, float* Out) {
    int l = blockIdx.x;
    int b = l & 7, it = (l >> 3) & 15, jh = l >> 7;
    int ibase = it * 128;
    int t = threadIdx.x;
    int lane = t & 63, wid = t >> 6;
    int lr = lane & 15, lg = lane >> 4;
    int ig = wid >> 1, jq = wid & 1;
    __shared__ __align__(16) bf16_t pool[26624];  // 52 KiB
    bf16_t* klds = pool;                          // 2 x 8192 elems (16 KiB each)
    bf16_t* pl = pool + 16384 + wid * 1280;       // [32 i][stride 40] per wave

    bf16x8 qf[2][4];
    int iblkg = (b * S + ibase + ig * 32) >> 4;
#pragma unroll
    for (int iF = 0; iF < 2; ++iF)
#pragma unroll
        for (int kk = 0; kk < 4; ++kk)
            qf[iF][kk] = *(const bf16x8*)(Qf + ((size_t)((iblkg + iF) * 4 + kk) * 64 + lane) * 8);

    f32x4 acc[2][8] = {};
    const bf16_t* kbase = Kf + (size_t)(b * S + jh * 1024) * 128;
    const bf16_t* vbase = Vt2 + (size_t)b * D * S;

    auto stageK = [&](int bufi, int tt) {
        const bf16_t* g = kbase + (size_t)tt * 8192 + wid * 1024 + lane * 8;
        __builtin_amdgcn_global_load_lds((gu32_t*)g, (lu32_t*)&klds[bufi * 8192 + wid * 1024], 16, 0, 0);
        __builtin_amdgcn_global_load_lds((gu32_t*)(g + 512), (lu32_t*)&klds[bufi * 8192 + wid * 1024 + 512], 16, 0, 0);
    };
    stageK(0, 0);
    __syncthreads();

    for (int tt = 0; tt < 16; ++tt) {
        int buf = tt & 1;
        if (tt < 15) stageK(buf ^ 1, tt + 1);
        int j32 = jh * 32 + tt * 2 + jq;
        bf16x8 vv[8];
#pragma unroll
        for (int dc = 0; dc < 8; ++dc)
            vv[dc] = *(const bf16x8*)(vbase + ((size_t)(j32 * 8 + dc) * 64 + lane) * 8);
#pragma unroll
        for (int jF = 0; jF < 2; ++jF) {
            bf16x8 ka[4];
#pragma unroll
            for (int kk = 0; kk < 4; ++kk)
                ka[kk] = *(const bf16x8*)&klds[buf * 8192 + ((jq * 2 + jF) * 4 + kk) * 512 + lane * 8];
#pragma unroll
            for (int iF = 0; iF < 2; ++iF) {
                f32x4 s = {};
                s = MFMA(ka[0], qf[iF][0], s);
                s = MFMA(ka[1], qf[iF][1], s);
                s = MFMA(ka[2], qf[iF][2], s);
                s = MFMA(ka[3], qf[iF][3], s);
                bf16x4 pv;
#pragma unroll
                for (int r = 0; r < 4; ++r) pv[r] = (bf16_t)exp2f(s[r] * C2);
                *(bf16x4*)&pl[(iF * 16 + lr) * 40 + jF * 16 + lg * 4] = pv;
            }
        }
        bf16x8 pa0 = *(const bf16x8*)&pl[lr * 40 + lg * 8];
        bf16x8 pa1 = *(const bf16x8*)&pl[(16 + lr) * 40 + lg * 8];
        __builtin_amdgcn_s_setprio(1);
#pragma unroll
        for (int dc = 0; dc < 8; ++dc) {
            acc[0][dc] = MFMA(pa0, vv[dc], acc[0][dc]);
            acc[1][dc] = MFMA(pa1, vv[dc], acc[1][dc]);
        }
        __builtin_amdgcn_s_setprio(0);
        __syncthreads();
    }

    // jq-pair reduce (two 16KB regions, 2 ig at a time), then one atomicAdd per elem
    float* R0 = (float*)pool;
    float* R1 = (float*)(pool + 8192);
    auto wrR = [&](float* R) {
#pragma unroll
        for (int iF = 0; iF < 2; ++iF)
#pragma unroll
            for (int dc = 0; dc < 8; ++dc)
#pragma unroll
                for (int r = 0; r < 4; ++r)
                    R[(iF * 16 + lg * 4 + r) * 128 + dc * 16 + lr] = acc[iF][dc][r];
    };
    auto adR = [&](float* R) {
#pragma unroll
        for (int iF = 0; iF < 2; ++iF)
#pragma unroll
            for (int dc = 0; dc < 8; ++dc)
#pragma unroll
                for (int r = 0; r < 4; ++r)
                    acc[iF][dc][r] += R[(iF * 16 + lg * 4 + r) * 128 + dc * 16 + lr];
    };
    if (jq == 1 && ig < 2) wrR(ig == 0 ? R0 : R1);
    __syncthreads();
    if (jq == 0 && ig < 2) adR(ig == 0 ? R0 : R1);
    __syncthreads();
    if (jq == 1 && ig >= 2) wrR(ig == 2 ? R0 : R1);
    __syncthreads();
    if (jq == 0 && ig >= 2) adR(ig == 2 ? R0 : R1);
    if (jq == 0) {
#pragma unroll
        for (int iF = 0; iF < 2; ++iF)
#pragma unroll
            for (int dc = 0; dc < 8; ++dc)
#pragma unroll
                for (int r = 0; r < 4; ++r)
                    atomicAdd(&Out[(size_t)(b * S + ibase + ig * 32 + iF * 16 + lg * 4 + r) * 128 + dc * 16 + lr],
                              acc[iF][dc][r]);
    }
}

extern "C" void kernel_launch(void* const* d_in, const int* in_sizes, int n_in,
                              void* d_out, int out_size, void* d_ws, size_t ws_size,
                              hipStream_t stream) {
    const float* X  = (const float*)d_in[0];
    const float* Wq = (const float*)d_in[1];
    const float* Wk = (const float*)d_in[2];
    const float* Wv = (const float*)d_in[3];
    char* ws = (char*)d_ws;
    bf16_t* Wf  = (bf16_t*)(ws);                 // 768 KiB (frag-major)
    bf16_t* Qf  = (bf16_t*)(ws + (1ull << 20));  // 4 MiB (frag-major)
    bf16_t* Kf  = (bf16_t*)(ws + (5ull << 20));  // 4 MiB (frag-major)
    float*  Vf  = (float*)(ws + (9ull << 20));   // 8 MiB (row-major fp32)
    bf16_t* Vt2 = (bf16_t*)(ws + (17ull << 20)); // 4 MiB (frag-major)
    float* Out = (float*)d_out;

    hipMemsetAsync(d_out, 0, (size_t)out_size * sizeof(float), stream);
    k_wt<<<dim3(64, 3), dim3(256), 0, stream>>>(Wq, Wk, Wv, Wf);
    k_qkv<<<dim3(256), dim3(512), 0, stream>>>(X, Wf, Qf, Kf, Vf);
    k_sum<<<dim3(256), dim3(512), 0, stream>>>(Qf, Kf, Vf, Vt2);
    k_out<<<dim3(256), dim3(512), 0, stream>>>(Qf, Kf, Vt2, Out);
}

// Round 7
// 88.628 us; speedup vs baseline: 1.9453x; 1.1720x over previous
//
#include <hip/hip_runtime.h>
#include <hip/hip_bf16.h>

typedef __bf16 bf16_t;
typedef bf16_t bf16x4 __attribute__((ext_vector_type(4)));
typedef bf16_t bf16x8 __attribute__((ext_vector_type(8)));
typedef float f32x4 __attribute__((ext_vector_type(4)));
typedef __attribute__((address_space(1))) const unsigned int gu32_t;
typedef __attribute__((address_space(3))) unsigned int lu32_t;

#define MFMA(a, b, c) __builtin_amdgcn_mfma_f32_16x16x32_bf16(a, b, c, 0, 0, 0)

constexpr int B = 8, S = 2048, C = 1024, D = 128;
constexpr float C2 = 0.12751744f; // log2(e)/sqrt(128)

// Frag-major: frag(blk16, kk) = 1KB block; lane = ((k>>3)&3)*16 + (dim&15),
// 8 contiguous k per lane. Serves both A- and B-operands of mfma_16x16x32.

// ---------------- K0: W[c][n] -> Wf frag-major ----------------------------
__global__ __launch_bounds__(256) void k_wt(const float* Wq, const float* Wk, const float* Wv, bf16_t* Wf) {
    int ct = blockIdx.x, w = blockIdx.y; // ct 0..63, w 0..2
    const float* src = (w == 0) ? Wq : ((w == 1) ? Wk : Wv);
    __shared__ bf16_t tile[16][132];
    int t = threadIdx.x;
    int cr = t >> 4, dq = t & 15;
    const float* p = src + (size_t)(ct * 16 + cr) * D + dq * 8;
    f32x4 v0 = *(const f32x4*)p;
    f32x4 v1 = *(const f32x4*)(p + 4);
#pragma unroll
    for (int q = 0; q < 4; ++q) { tile[cr][dq * 8 + q] = (bf16_t)v0[q]; tile[cr][dq * 8 + 4 + q] = (bf16_t)v1[q]; }
    __syncthreads();
    int n = t >> 1, g = t & 1;
    bf16x8 o;
#pragma unroll
    for (int cc = 0; cc < 8; ++cc) o[cc] = tile[g * 8 + cc][n];
    int c8 = ct * 2 + g;
    int nblk = w * 8 + (n >> 4);
    size_t a = ((size_t)(nblk * 32 + (c8 >> 2)) * 64 + (c8 & 3) * 16 + (n & 15)) * 8;
    *(bf16x8*)(Wf + a) = o;
}

// ---------------- K1: fused QKV projection, 512 blocks x 32 rows ----------
// 8 waves x 48 cols; X LDS dbuf; W frags register-double-buffered from L2.
__global__ __launch_bounds__(512, 4) void k_qkv(const float* X, const bf16_t* Wf,
                                                bf16_t* Qf, bf16_t* Kf, float* Vf) {
    __shared__ __align__(16) bf16_t xs[2][2048]; // [8 kc][32 rows][8 k], 4 KiB each
    int mt = blockIdx.x; // 0..511
    int t = threadIdx.x;
    int lane = t & 63, wid = t >> 6;
    int lr = lane & 15, lg = lane >> 4;
    int rw = mt * 32;
    int xrow = t >> 4, xk = t & 15;
    const float* xsrc = X + (size_t)(rw + xrow) * C + xk * 4;
    int xwi = ((xk >> 1) * 32 + xrow) * 8 + (xk & 1) * 4;

    f32x4 acc[2][3] = {};

    auto wfrag = [&](int nf, int kk32) {
        return *(const bf16x8*)(Wf + ((size_t)((wid * 3 + nf) * 32 + kk32) * 64 + lane) * 8);
    };

    bf16x8 wA[2][3], wB[2][3];
#pragma unroll
    for (int kh = 0; kh < 2; ++kh)
#pragma unroll
        for (int nf = 0; nf < 3; ++nf) wA[kh][nf] = wfrag(nf, kh);
    {
        f32x4 x = *(const f32x4*)xsrc;
        bf16x4 xv;
#pragma unroll
        for (int q = 0; q < 4; ++q) xv[q] = (bf16_t)x[q];
        *(bf16x4*)&xs[0][xwi] = xv;
    }
    __syncthreads();

    for (int tt = 0; tt < 16; tt += 2) {
        { // even: compute xs[0] with wA; prefetch tt+1 (W->wB, X->xs[1])
#pragma unroll
            for (int kh = 0; kh < 2; ++kh)
#pragma unroll
                for (int nf = 0; nf < 3; ++nf) wB[kh][nf] = wfrag(nf, (tt + 1) * 2 + kh);
            f32x4 xp = *(const f32x4*)(xsrc + (tt + 1) * 64);
#pragma unroll
            for (int kh = 0; kh < 2; ++kh) {
                bf16x8 a0 = *(bf16x8*)&xs[0][((kh * 4 + lg) * 32 + lr) * 8];
                bf16x8 a1 = *(bf16x8*)&xs[0][((kh * 4 + lg) * 32 + 16 + lr) * 8];
#pragma unroll
                for (int nf = 0; nf < 3; ++nf) {
                    acc[0][nf] = MFMA(a0, wA[kh][nf], acc[0][nf]);
                    acc[1][nf] = MFMA(a1, wA[kh][nf], acc[1][nf]);
                }
            }
            bf16x4 xv;
#pragma unroll
            for (int q = 0; q < 4; ++q) xv[q] = (bf16_t)xp[q];
            *(bf16x4*)&xs[1][xwi] = xv;
            __syncthreads();
        }
        { // odd: compute xs[1] with wB; prefetch tt+2 (W->wA, X->xs[0])
            bool pf = (tt + 2) < 16;
            f32x4 xq;
            if (pf) {
#pragma unroll
                for (int kh = 0; kh < 2; ++kh)
#pragma unroll
                    for (int nf = 0; nf < 3; ++nf) wA[kh][nf] = wfrag(nf, (tt + 2) * 2 + kh);
                xq = *(const f32x4*)(xsrc + (tt + 2) * 64);
            }
#pragma unroll
            for (int kh = 0; kh < 2; ++kh) {
                bf16x8 a0 = *(bf16x8*)&xs[1][((kh * 4 + lg) * 32 + lr) * 8];
                bf16x8 a1 = *(bf16x8*)&xs[1][((kh * 4 + lg) * 32 + 16 + lr) * 8];
#pragma unroll
                for (int nf = 0; nf < 3; ++nf) {
                    acc[0][nf] = MFMA(a0, wB[kh][nf], acc[0][nf]);
                    acc[1][nf] = MFMA(a1, wB[kh][nf], acc[1][nf]);
                }
            }
            if (pf) {
                bf16x4 xv;
#pragma unroll
                for (int q = 0; q < 4; ++q) xv[q] = (bf16_t)xq[q];
                *(bf16x4*)&xs[0][xwi] = xv;
            }
            __syncthreads();
        }
    }
#pragma unroll
    for (int mi = 0; mi < 2; ++mi)
#pragma unroll
        for (int nf = 0; nf < 3; ++nf) {
            int n = wid * 48 + nf * 16 + lr;
            int sel = (wid * 48 + nf * 16) >> 7; // wave-uniform
            int nn = n & 127;
#pragma unroll
            for (int r = 0; r < 4; ++r) {
                int m = rw + mi * 16 + lg * 4 + r;
                float v = acc[mi][nf][r];
                if (sel == 2) {
                    Vf[(size_t)m * D + nn] = v;
                } else {
                    bf16_t* dst = (sel == 0) ? Qf : Kf;
                    size_t a = ((size_t)((m >> 4) * 4 + (nn >> 5)) * 64 + ((nn >> 3) & 3) * 16 + (m & 15)) * 8 + (nn & 7);
                    dst[a] = (bf16_t)v;
                }
            }
        }
}

// ---------------- K2: column sums l[j] (32 j/block) + V scale/transpose ----
__global__ __launch_bounds__(512, 4) void k_sum(const bf16_t* Qf, const bf16_t* Kf,
                                                const float* Vf, bf16_t* Vt2) {
    int l = blockIdx.x;          // 512 blocks
    int b = l & 7, jt = l >> 3;  // b pinned to XCD; jt 0..63
    int j0 = jt * 32;
    int t = threadIdx.x;
    int lane = t & 63, wid = t >> 6;
    __shared__ __align__(16) bf16_t qs[2][16384]; // 2 x 32 KiB
    bf16_t* vtile = qs[0];                        // [128 d][stride 40] (alias)
    float* lsum = (float*)(qs[0] + 6144);
    float* linv = (float*)(qs[0] + 6656);

    bf16x8 kf[2][4];
    int jblkg = (b * S + j0) >> 4;
#pragma unroll
    for (int jF = 0; jF < 2; ++jF)
#pragma unroll
        for (int kk = 0; kk < 4; ++kk)
            kf[jF][kk] = *(const bf16x8*)(Kf + ((size_t)((jblkg + jF) * 4 + kk) * 64 + lane) * 8);

    const bf16_t* qsrc = Qf + (size_t)(b * S) * 128;
    auto stageQ = [&](int bufi, int i0) {
#pragma unroll
        for (int i = 0; i < 4; ++i)
            __builtin_amdgcn_global_load_lds(
                (gu32_t*)(qsrc + (size_t)i0 * 128 + wid * 2048 + i * 512 + lane * 8),
                (lu32_t*)&qs[bufi][wid * 2048 + i * 512], 16, 0, 0);
    };

    float ls0 = 0.f, ls1 = 0.f;
    stageQ(0, 0);
    __syncthreads();
    for (int tt = 0; tt < 16; ++tt) {
        int buf = tt & 1;
        if (tt < 15) stageQ(buf ^ 1, (tt + 1) * 128);
        bf16x8 qa[4];
#pragma unroll
        for (int kk = 0; kk < 4; ++kk)
            qa[kk] = *(const bf16x8*)&qs[buf][(wid * 4 + kk) * 512 + lane * 8];
        f32x4 s0 = {}, s1 = {};
#pragma unroll
        for (int kk = 0; kk < 4; ++kk) {
            s0 = MFMA(qa[kk], kf[0][kk], s0);
            s1 = MFMA(qa[kk], kf[1][kk], s1);
        }
#pragma unroll
        for (int r = 0; r < 4; ++r) { ls0 += exp2f(s0[r] * C2); ls1 += exp2f(s1[r] * C2); }
        __syncthreads();
    }
    {
        float v0 = ls0 + __shfl_xor(ls0, 16); v0 += __shfl_xor(v0, 32);
        float v1 = ls1 + __shfl_xor(ls1, 16); v1 += __shfl_xor(v1, 32);
        if (lane < 16) { lsum[wid * 32 + lane] = v0; lsum[wid * 32 + 16 + lane] = v1; }
    }
    __syncthreads();
    if (t < 32) {
        float ss = 0.f;
#pragma unroll
        for (int w = 0; w < 8; ++w) ss += lsum[w * 32 + t];
        linv[t] = 1.0f / ss;
    }
    __syncthreads();
    // scale + transpose V into pad-40 vtile (no swizzle needed; ~2-way banks)
#pragma unroll
    for (int p = 0; p < 2; ++p) {
        int u = p * 512 + t;
        int jj = u & 31, dq = u >> 5; // dq 0..31 over 2 passes
        f32x4 v = *(const f32x4*)(Vf + (size_t)(b * S + j0 + jj) * D + dq * 4);
        float inv = linv[jj];
#pragma unroll
        for (int q = 0; q < 4; ++q)
            vtile[(dq * 4 + q) * 40 + jj] = (bf16_t)(v[q] * inv);
    }
    __syncthreads();
    {
        int d = t >> 2, jg = t & 3;
        bf16x8 row = *(const bf16x8*)&vtile[d * 40 + jg * 8];
        size_t j32g = (size_t)b * 64 + jt;
        size_t a = ((j32g * 8 + (d >> 4)) * 64 + jg * 16 + (d & 15)) * 8;
        *(bf16x8*)(Vt2 + a) = row;
    }
}

// ---------------- K3: out = exp2(c*QK^T) @ Vdiv ---------------------------
// 512 blocks = 8 b x 32 it(64 i) x 2 jh; 8 waves = 4 ig(16 i) x 2 jq(32 j/step).
// K AND V LDS-staged (linear frag-stream copies), 74 KiB -> 2 blocks/CU.
__global__ __launch_bounds__(512, 4) void k_out(const bf16_t* Qf, const bf16_t* Kf,
                                                const bf16_t* Vt2, float* Out) {
    int l = blockIdx.x;            // 512 blocks
    int b = l & 7, it = (l >> 3) & 31, jh = l >> 8;
    int ibase = it * 64;
    int t = threadIdx.x;
    int lane = t & 63, wid = t >> 6;
    int lr = lane & 15, lg = lane >> 4;
    int ig = wid >> 1, jq = wid & 1;
    __shared__ __align__(16) bf16_t pool[37888]; // 74 KiB
    bf16_t* klds = pool;                          // 2 x 8192 elems
    bf16_t* vlds = pool + 16384;                  // 2 x 8192 elems
    bf16_t* pl = pool + 32768 + wid * 640;        // [16 i][stride 40] per wave

    bf16x8 qf[4];
    int iblk = (b * S + ibase + ig * 16) >> 4;
#pragma unroll
    for (int kk = 0; kk < 4; ++kk)
        qf[kk] = *(const bf16x8*)(Qf + ((size_t)(iblk * 4 + kk) * 64 + lane) * 8);

    f32x4 acc[8] = {};
    const bf16_t* kbase = Kf + (size_t)(b * S + jh * 1024) * 128 + wid * 1024 + lane * 8;
    const bf16_t* vbase = Vt2 + (size_t)(b * 64 + jh * 32) * 4096 + wid * 1024 + lane * 8;

    auto stageKV = [&](int bufi, int tt) {
        const bf16_t* gk = kbase + (size_t)tt * 8192;
        __builtin_amdgcn_global_load_lds((gu32_t*)gk, (lu32_t*)&klds[bufi * 8192 + wid * 1024], 16, 0, 0);
        __builtin_amdgcn_global_load_lds((gu32_t*)(gk + 512), (lu32_t*)&klds[bufi * 8192 + wid * 1024 + 512], 16, 0, 0);
        const bf16_t* gv = vbase + (size_t)tt * 8192;
        __builtin_amdgcn_global_load_lds((gu32_t*)gv, (lu32_t*)&vlds[bufi * 8192 + wid * 1024], 16, 0, 0);
        __builtin_amdgcn_global_load_lds((gu32_t*)(gv + 512), (lu32_t*)&vlds[bufi * 8192 + wid * 1024 + 512], 16, 0, 0);
    };
    stageKV(0, 0);
    __syncthreads();

    for (int tt = 0; tt < 16; ++tt) {
        int buf = tt & 1;
        if (tt < 15) stageKV(buf ^ 1, tt + 1);
#pragma unroll
        for (int jF = 0; jF < 2; ++jF) {
            const bf16_t* kl = &klds[buf * 8192 + ((jq * 2 + jF) * 4) * 512 + lane * 8];
            // swapped QK^T: lane holds S^T[j = (jq*2+jF)*16 + lg*4+r][i = lr]
            f32x4 s = {};
            s = MFMA(*(const bf16x8*)(kl), qf[0], s);
            s = MFMA(*(const bf16x8*)(kl + 512), qf[1], s);
            s = MFMA(*(const bf16x8*)(kl + 1024), qf[2], s);
            s = MFMA(*(const bf16x8*)(kl + 1536), qf[3], s);
            bf16x4 pv;
#pragma unroll
            for (int r = 0; r < 4; ++r) pv[r] = (bf16_t)exp2f(s[r] * C2);
            *(bf16x4*)&pl[lr * 40 + jF * 16 + lg * 4] = pv;
        }
        bf16x8 pa = *(const bf16x8*)&pl[lr * 40 + lg * 8];
        const bf16_t* vl = &vlds[buf * 8192 + jq * 4096 + lane * 8];
        __builtin_amdgcn_s_setprio(1);
#pragma unroll
        for (int dc = 0; dc < 8; ++dc)
            acc[dc] = MFMA(pa, *(const bf16x8*)(vl + dc * 512), acc[dc]);
        __builtin_amdgcn_s_setprio(0);
        __syncthreads();
    }

    float* R = (float*)pool + ig * 2048; // 4 regions x 8 KiB, alias klds (dead)
    if (jq == 1) {
#pragma unroll
        for (int dc = 0; dc < 8; ++dc)
#pragma unroll
            for (int r = 0; r < 4; ++r)
                R[(lg * 4 + r) * 128 + dc * 16 + lr] = acc[dc][r];
    }
    __syncthreads();
    if (jq == 0) {
#pragma unroll
        for (int dc = 0; dc < 8; ++dc)
#pragma unroll
            for (int r = 0; r < 4; ++r)
                atomicAdd(&Out[(size_t)(b * S + ibase + ig * 16 + lg * 4 + r) * 128 + dc * 16 + lr],
                          acc[dc][r] + R[(lg * 4 + r) * 128 + dc * 16 + lr]);
    }
}

extern "C" void kernel_launch(void* const* d_in, const int* in_sizes, int n_in,
                              void* d_out, int out_size, void* d_ws, size_t ws_size,
                              hipStream_t stream) {
    const float* X  = (const float*)d_in[0];
    const float* Wq = (const float*)d_in[1];
    const float* Wk = (const float*)d_in[2];
    const float* Wv = (const float*)d_in[3];
    char* ws = (char*)d_ws;
    bf16_t* Wf  = (bf16_t*)(ws);                 // 768 KiB (frag-major)
    bf16_t* Qf  = (bf16_t*)(ws + (1ull << 20));  // 4 MiB (frag-major)
    bf16_t* Kf  = (bf16_t*)(ws + (5ull << 20));  // 4 MiB (frag-major)
    float*  Vf  = (float*)(ws + (9ull << 20));   // 8 MiB (row-major fp32)
    bf16_t* Vt2 = (bf16_t*)(ws + (17ull << 20)); // 4 MiB (frag-major)
    float* Out = (float*)d_out;

    hipMemsetAsync(d_out, 0, (size_t)out_size * sizeof(float), stream);
    k_wt<<<dim3(64, 3), dim3(256), 0, stream>>>(Wq, Wk, Wv, Wf);
    k_qkv<<<dim3(512), dim3(512), 0, stream>>>(X, Wf, Qf, Kf, Vf);
    k_sum<<<dim3(512), dim3(512), 0, stream>>>(Qf, Kf, Vf, Vt2);
    k_out<<<dim3(512), dim3(512), 0, stream>>>(Qf, Kf, Vt2, Out);
}

// Round 8
// 86.578 us; speedup vs baseline: 1.9914x; 1.0237x over previous
//
#include <hip/hip_runtime.h>
#include <hip/hip_bf16.h>

typedef __bf16 bf16_t;
typedef bf16_t bf16x4 __attribute__((ext_vector_type(4)));
typedef bf16_t bf16x8 __attribute__((ext_vector_type(8)));
typedef float f32x4 __attribute__((ext_vector_type(4)));
typedef __attribute__((address_space(1))) const unsigned int gu32_t;
typedef __attribute__((address_space(3))) unsigned int lu32_t;

#define MFMA(a, b, c) __builtin_amdgcn_mfma_f32_16x16x32_bf16(a, b, c, 0, 0, 0)

constexpr int B = 8, S = 2048, C = 1024, D = 128;
constexpr float C2 = 0.12751744f; // log2(e)/sqrt(128)

// Frag-major: frag(blk16, kk) = 1KB block; lane = ((k>>3)&3)*16 + (dim&15),
// 8 contiguous k per lane. Serves both A- and B-operands of mfma_16x16x32.

// ---------------- K0: W[c][n] -> Wf frag-major ----------------------------
__global__ __launch_bounds__(256) void k_wt(const float* Wq, const float* Wk, const float* Wv, bf16_t* Wf) {
    int ct = blockIdx.x, w = blockIdx.y; // ct 0..63, w 0..2
    const float* src = (w == 0) ? Wq : ((w == 1) ? Wk : Wv);
    __shared__ bf16_t tile[16][132];
    int t = threadIdx.x;
    int cr = t >> 4, dq = t & 15;
    const float* p = src + (size_t)(ct * 16 + cr) * D + dq * 8;
    f32x4 v0 = *(const f32x4*)p;
    f32x4 v1 = *(const f32x4*)(p + 4);
#pragma unroll
    for (int q = 0; q < 4; ++q) { tile[cr][dq * 8 + q] = (bf16_t)v0[q]; tile[cr][dq * 8 + 4 + q] = (bf16_t)v1[q]; }
    __syncthreads();
    int n = t >> 1, g = t & 1;
    bf16x8 o;
#pragma unroll
    for (int cc = 0; cc < 8; ++cc) o[cc] = tile[g * 8 + cc][n];
    int c8 = ct * 2 + g;
    int nblk = w * 8 + (n >> 4);
    size_t a = ((size_t)(nblk * 32 + (c8 >> 2)) * 64 + (c8 & 3) * 16 + (n & 15)) * 8;
    *(bf16x8*)(Wf + a) = o;
}

// ---------------- K1: fused QKV projection, 512 blocks x 32 rows ----------
// 8 waves x 48 cols; X LDS dbuf with DEPTH-3 reg pipeline; W frags reg-dbuf.
// Also zeroes Out (replaces 42us hipMemsetAsync; k_out atomicAdds later).
__global__ __launch_bounds__(512, 4) void k_qkv(const float* X, const bf16_t* Wf,
                                                bf16_t* Qf, bf16_t* Kf, float* Vf,
                                                float* Out) {
    __shared__ __align__(16) bf16_t xs[2][2048]; // [8 kc][32 rows][8 k], 4 KiB each
    int mt = blockIdx.x; // 0..511
    int t = threadIdx.x;
    int lane = t & 63, wid = t >> 6;
    int lr = lane & 15, lg = lane >> 4;
    int rw = mt * 32;
    int xrow = t >> 4, xk = t & 15;
    const float* xsrc = X + (size_t)(rw + xrow) * C + xk * 4;
    int xwi = ((xk >> 1) * 32 + xrow) * 8 + (xk & 1) * 4;

    { // zero Out: 512*512 threads x 2 f32x4 = 32 MiB
        f32x4* O4 = (f32x4*)Out;
        f32x4 z = {};
        int u = mt * 512 + t;
        O4[u] = z;
        O4[u + 262144] = z;
    }

    f32x4 acc[2][3] = {};

    auto wfrag = [&](int nf, int kk32) {
        return *(const bf16x8*)(Wf + ((size_t)((wid * 3 + nf) * 32 + kk32) * 64 + lane) * 8);
    };
    auto xld = [&](int s) { return *(const f32x4*)(xsrc + s * 64); };
    auto xst = [&](int bufi, f32x4 xv) {
        bf16x4 c;
#pragma unroll
        for (int q = 0; q < 4; ++q) c[q] = (bf16_t)xv[q];
        *(bf16x4*)&xs[bufi][xwi] = c;
    };

    bf16x8 wCur[2][3];
#pragma unroll
    for (int kh = 0; kh < 2; ++kh)
#pragma unroll
        for (int nf = 0; nf < 3; ++nf) wCur[kh][nf] = wfrag(nf, kh);
    xst(0, xld(0));
    f32x4 xP1 = xld(1), xP2 = xld(2);
    __syncthreads();

#pragma unroll
    for (int tt = 0; tt < 16; ++tt) {
        int buf = tt & 1;
        bf16x8 wNxt[2][3];
        if (tt < 15) {
#pragma unroll
            for (int kh = 0; kh < 2; ++kh)
#pragma unroll
                for (int nf = 0; nf < 3; ++nf) wNxt[kh][nf] = wfrag(nf, (tt + 1) * 2 + kh);
        }
        f32x4 xNext = {};
        if (tt < 13) xNext = xld(tt + 3);
#pragma unroll
        for (int kh = 0; kh < 2; ++kh) {
            bf16x8 a0 = *(bf16x8*)&xs[buf][((kh * 4 + lg) * 32 + lr) * 8];
            bf16x8 a1 = *(bf16x8*)&xs[buf][((kh * 4 + lg) * 32 + 16 + lr) * 8];
#pragma unroll
            for (int nf = 0; nf < 3; ++nf) {
                acc[0][nf] = MFMA(a0, wCur[kh][nf], acc[0][nf]);
                acc[1][nf] = MFMA(a1, wCur[kh][nf], acc[1][nf]);
            }
        }
        if (tt < 15) {
            xst(buf ^ 1, xP1);
#pragma unroll
            for (int kh = 0; kh < 2; ++kh)
#pragma unroll
                for (int nf = 0; nf < 3; ++nf) wCur[kh][nf] = wNxt[kh][nf];
        }
        xP1 = xP2; xP2 = xNext;
        __syncthreads();
    }
#pragma unroll
    for (int mi = 0; mi < 2; ++mi)
#pragma unroll
        for (int nf = 0; nf < 3; ++nf) {
            int n = wid * 48 + nf * 16 + lr;
            int sel = (wid * 48 + nf * 16) >> 7; // wave-uniform
            int nn = n & 127;
#pragma unroll
            for (int r = 0; r < 4; ++r) {
                int m = rw + mi * 16 + lg * 4 + r;
                float v = acc[mi][nf][r];
                if (sel == 2) {
                    Vf[(size_t)m * D + nn] = v;
                } else {
                    bf16_t* dst = (sel == 0) ? Qf : Kf;
                    size_t a = ((size_t)((m >> 4) * 4 + (nn >> 5)) * 64 + ((nn >> 3) & 3) * 16 + (m & 15)) * 8 + (nn & 7);
                    dst[a] = (bf16_t)v;
                }
            }
        }
}

// ---------------- K2: column sums l[j] (32 j/block) + V scale/transpose ----
__global__ __launch_bounds__(512, 4) void k_sum(const bf16_t* Qf, const bf16_t* Kf,
                                                const float* Vf, bf16_t* Vt2) {
    int l = blockIdx.x;          // 512 blocks
    int b = l & 7, jt = l >> 3;  // b pinned to XCD; jt 0..63
    int j0 = jt * 32;
    int t = threadIdx.x;
    int lane = t & 63, wid = t >> 6;
    __shared__ __align__(16) bf16_t qs[2][16384]; // 2 x 32 KiB
    bf16_t* vtile = qs[0];                        // [128 d][stride 40] (alias)
    float* lsum = (float*)(qs[0] + 6144);
    float* linv = (float*)(qs[0] + 6656);

    bf16x8 kf[2][4];
    int jblkg = (b * S + j0) >> 4;
#pragma unroll
    for (int jF = 0; jF < 2; ++jF)
#pragma unroll
        for (int kk = 0; kk < 4; ++kk)
            kf[jF][kk] = *(const bf16x8*)(Kf + ((size_t)((jblkg + jF) * 4 + kk) * 64 + lane) * 8);

    const bf16_t* qsrc = Qf + (size_t)(b * S) * 128;
    auto stageQ = [&](int bufi, int i0) {
#pragma unroll
        for (int i = 0; i < 4; ++i)
            __builtin_amdgcn_global_load_lds(
                (gu32_t*)(qsrc + (size_t)i0 * 128 + wid * 2048 + i * 512 + lane * 8),
                (lu32_t*)&qs[bufi][wid * 2048 + i * 512], 16, 0, 0);
    };

    float ls0 = 0.f, ls1 = 0.f;
    stageQ(0, 0);
    __syncthreads();
    for (int tt = 0; tt < 16; ++tt) {
        int buf = tt & 1;
        if (tt < 15) stageQ(buf ^ 1, (tt + 1) * 128);
        bf16x8 qa[4];
#pragma unroll
        for (int kk = 0; kk < 4; ++kk)
            qa[kk] = *(const bf16x8*)&qs[buf][(wid * 4 + kk) * 512 + lane * 8];
        f32x4 s0 = {}, s1 = {};
#pragma unroll
        for (int kk = 0; kk < 4; ++kk) {
            s0 = MFMA(qa[kk], kf[0][kk], s0);
            s1 = MFMA(qa[kk], kf[1][kk], s1);
        }
#pragma unroll
        for (int r = 0; r < 4; ++r) { ls0 += exp2f(s0[r] * C2); ls1 += exp2f(s1[r] * C2); }
        __syncthreads();
    }
    {
        float v0 = ls0 + __shfl_xor(ls0, 16); v0 += __shfl_xor(v0, 32);
        float v1 = ls1 + __shfl_xor(ls1, 16); v1 += __shfl_xor(v1, 32);
        if (lane < 16) { lsum[wid * 32 + lane] = v0; lsum[wid * 32 + 16 + lane] = v1; }
    }
    __syncthreads();
    if (t < 32) {
        float ss = 0.f;
#pragma unroll
        for (int w = 0; w < 8; ++w) ss += lsum[w * 32 + t];
        linv[t] = 1.0f / ss;
    }
    __syncthreads();
    // scale + transpose V into pad-40 vtile (~2-way banks)
#pragma unroll
    for (int p = 0; p < 2; ++p) {
        int u = p * 512 + t;
        int jj = u & 31, dq = u >> 5;
        f32x4 v = *(const f32x4*)(Vf + (size_t)(b * S + j0 + jj) * D + dq * 4);
        float inv = linv[jj];
#pragma unroll
        for (int q = 0; q < 4; ++q)
            vtile[(dq * 4 + q) * 40 + jj] = (bf16_t)(v[q] * inv);
    }
    __syncthreads();
    {
        int d = t >> 2, jg = t & 3;
        bf16x8 row = *(const bf16x8*)&vtile[d * 40 + jg * 8];
        size_t j32g = (size_t)b * 64 + jt;
        size_t a = ((j32g * 8 + (d >> 4)) * 64 + jg * 16 + (d & 15)) * 8;
        *(bf16x8*)(Vt2 + a) = row;
    }
}

// ---------------- K3: out = exp2(c*QK^T) @ Vdiv ---------------------------
// 512 blocks = 8 b x 32 it(64 i) x 2 jh; 8 waves = 4 ig(16 i) x 2 jq(32 j/step).
// K AND V LDS-staged (linear frag-stream copies), 74 KiB -> 2 blocks/CU.
__global__ __launch_bounds__(512, 4) void k_out(const bf16_t* Qf, const bf16_t* Kf,
                                                const bf16_t* Vt2, float* Out) {
    int l = blockIdx.x;            // 512 blocks
    int b = l & 7, it = (l >> 3) & 31, jh = l >> 8;
    int ibase = it * 64;
    int t = threadIdx.x;
    int lane = t & 63, wid = t >> 6;
    int lr = lane & 15, lg = lane >> 4;
    int ig = wid >> 1, jq = wid & 1;
    __shared__ __align__(16) bf16_t pool[37888]; // 74 KiB
    bf16_t* klds = pool;                          // 2 x 8192 elems
    bf16_t* vlds = pool + 16384;                  // 2 x 8192 elems
    bf16_t* pl = pool + 32768 + wid * 640;        // [16 i][stride 40] per wave

    bf16x8 qf[4];
    int iblk = (b * S + ibase + ig * 16) >> 4;
#pragma unroll
    for (int kk = 0; kk < 4; ++kk)
        qf[kk] = *(const bf16x8*)(Qf + ((size_t)(iblk * 4 + kk) * 64 + lane) * 8);

    f32x4 acc[8] = {};
    const bf16_t* kbase = Kf + (size_t)(b * S + jh * 1024) * 128 + wid * 1024 + lane * 8;
    const bf16_t* vbase = Vt2 + (size_t)(b * 64 + jh * 32) * 4096 + wid * 1024 + lane * 8;

    auto stageKV = [&](int bufi, int tt) {
        const bf16_t* gk = kbase + (size_t)tt * 8192;
        __builtin_amdgcn_global_load_lds((gu32_t*)gk, (lu32_t*)&klds[bufi * 8192 + wid * 1024], 16, 0, 0);
        __builtin_amdgcn_global_load_lds((gu32_t*)(gk + 512), (lu32_t*)&klds[bufi * 8192 + wid * 1024 + 512], 16, 0, 0);
        const bf16_t* gv = vbase + (size_t)tt * 8192;
        __builtin_amdgcn_global_load_lds((gu32_t*)gv, (lu32_t*)&vlds[bufi * 8192 + wid * 1024], 16, 0, 0);
        __builtin_amdgcn_global_load_lds((gu32_t*)(gv + 512), (lu32_t*)&vlds[bufi * 8192 + wid * 1024 + 512], 16, 0, 0);
    };
    stageKV(0, 0);
    __syncthreads();

    for (int tt = 0; tt < 16; ++tt) {
        int buf = tt & 1;
        if (tt < 15) stageKV(buf ^ 1, tt + 1);
#pragma unroll
        for (int jF = 0; jF < 2; ++jF) {
            const bf16_t* kl = &klds[buf * 8192 + ((jq * 2 + jF) * 4) * 512 + lane * 8];
            // swapped QK^T: lane holds S^T[j = (jq*2+jF)*16 + lg*4+r][i = lr]
            f32x4 s = {};
            s = MFMA(*(const bf16x8*)(kl), qf[0], s);
            s = MFMA(*(const bf16x8*)(kl + 512), qf[1], s);
            s = MFMA(*(const bf16x8*)(kl + 1024), qf[2], s);
            s = MFMA(*(const bf16x8*)(kl + 1536), qf[3], s);
            bf16x4 pv;
#pragma unroll
            for (int r = 0; r < 4; ++r) pv[r] = (bf16_t)exp2f(s[r] * C2);
            *(bf16x4*)&pl[lr * 40 + jF * 16 + lg * 4] = pv;
        }
        bf16x8 pa = *(const bf16x8*)&pl[lr * 40 + lg * 8];
        const bf16_t* vl = &vlds[buf * 8192 + jq * 4096 + lane * 8];
        __builtin_amdgcn_s_setprio(1);
#pragma unroll
        for (int dc = 0; dc < 8; ++dc)
            acc[dc] = MFMA(pa, *(const bf16x8*)(vl + dc * 512), acc[dc]);
        __builtin_amdgcn_s_setprio(0);
        __syncthreads();
    }

    float* R = (float*)pool + ig * 2048; // 4 regions x 8 KiB, alias klds (dead)
    if (jq == 1) {
#pragma unroll
        for (int dc = 0; dc < 8; ++dc)
#pragma unroll
            for (int r = 0; r < 4; ++r)
                R[(lg * 4 + r) * 128 + dc * 16 + lr] = acc[dc][r];
    }
    __syncthreads();
    if (jq == 0) {
#pragma unroll
        for (int dc = 0; dc < 8; ++dc)
#pragma unroll
            for (int r = 0; r < 4; ++r)
                atomicAdd(&Out[(size_t)(b * S + ibase + ig * 16 + lg * 4 + r) * 128 + dc * 16 + lr],
                          acc[dc][r] + R[(lg * 4 + r) * 128 + dc * 16 + lr]);
    }
}

extern "C" void kernel_launch(void* const* d_in, const int* in_sizes, int n_in,
                              void* d_out, int out_size, void* d_ws, size_t ws_size,
                              hipStream_t stream) {
    const float* X  = (const float*)d_in[0];
    const float* Wq = (const float*)d_in[1];
    const float* Wk = (const float*)d_in[2];
    const float* Wv = (const float*)d_in[3];
    char* ws = (char*)d_ws;
    bf16_t* Wf  = (bf16_t*)(ws);                 // 768 KiB (frag-major)
    bf16_t* Qf  = (bf16_t*)(ws + (1ull << 20));  // 4 MiB (frag-major)
    bf16_t* Kf  = (bf16_t*)(ws + (5ull << 20));  // 4 MiB (frag-major)
    float*  Vf  = (float*)(ws + (9ull << 20));   // 8 MiB (row-major fp32)
    bf16_t* Vt2 = (bf16_t*)(ws + (17ull << 20)); // 4 MiB (frag-major)
    float* Out = (float*)d_out;

    k_wt<<<dim3(64, 3), dim3(256), 0, stream>>>(Wq, Wk, Wv, Wf);
    k_qkv<<<dim3(512), dim3(512), 0, stream>>>(X, Wf, Qf, Kf, Vf, Out);
    k_sum<<<dim3(512), dim3(512), 0, stream>>>(Qf, Kf, Vf, Vt2);
    k_out<<<dim3(512), dim3(512), 0, stream>>>(Qf, Kf, Vt2, Out);
}